// Round 13
// baseline (574.471 us; speedup 1.0000x reference)
//
#include <hip/hip_runtime.h>
#include <hip/hip_bf16.h>

// AUGRU dynamic RNN: B=1024, T=512, D=128.
// 64 blocks x 512 threads (8 waves, TLP=2/SIMD); block owns 16 batch rows.
// Base = R9 (525.8us best). Round-13: REGION REBALANCE (placement only).
//  * The 12 h-independent x-partial MFMAs (n0/n1/n2) + their axn reads move
//    from the P1 region to the P2 region, issued after the 4-deep cc chain:
//    they run on the matrix pipe UNDER the update-phase VALU. Region MFMA
//    load goes 20/4 -> 8/16 (P1 was MFMA-bound while P2's matrix pipe idled).
//  * Barrier 2 uses counted lgkmcnt(1): write queue is [hb x4, xb, abuf];
//    the one op left in flight (xb for most lanes, abuf for tid<16) is
//    consumed only after its writer's next lgkmcnt(0) at barrier 1 -> safe.
//  * OUT addresses as running offsets; abuf stores (1-a) directly.
// Math bit-identical to R9: R5 cross-step partials, column-aligned gates +
// register h, cvt_pk_bf16, folded biases, lgkm-only barriers.

#define Bn 1024
#define Tn 512
#define Dn 128

typedef __attribute__((ext_vector_type(8))) short short8;   // 8 bf16 (4 VGPR)
typedef __attribute__((ext_vector_type(4))) float f32x4;

#define BS 136   // bf16 LDS row stride (shorts): 272 B = 17*16B

#define NL2E  (-1.4426950408889634f)   // -log2(e)
#define N2L2E (-2.8853900817779268f)   // -2*log2(e)

__device__ __forceinline__ short f2bf(float f) {            // cold paths only
    __hip_bfloat16 h = __float2bfloat16(f);   // RNE
    return __builtin_bit_cast(short, h);
}
__device__ __forceinline__ unsigned cvt_pk_bf16(float a, float b) {
    unsigned r;
    asm("v_cvt_pk_bf16_f32 %0, %1, %2" : "=v"(r) : "v"(a), "v"(b));
    return r;
}
// LDS-only barrier: order LDS ops across waves WITHOUT draining vmcnt.
__device__ __forceinline__ void barrier_lds() {
    __builtin_amdgcn_sched_barrier(0);
    asm volatile("s_waitcnt lgkmcnt(0)" ::: "memory");
    __builtin_amdgcn_s_barrier();
    __builtin_amdgcn_sched_barrier(0);
}
// Counted variant: allow the LAST queued DS write (xb stage / abuf) to stay
// in flight across the barrier; it drains at the wave's next lgkmcnt(0)
// before any consumer can read it (consumers read 2+ barriers later).
__device__ __forceinline__ void barrier_lds_c1() {
    __builtin_amdgcn_sched_barrier(0);
    asm volatile("s_waitcnt lgkmcnt(1)" ::: "memory");
    __builtin_amdgcn_s_barrier();
    __builtin_amdgcn_sched_barrier(0);
}

#define MFMA_(a, b, c) __builtin_amdgcn_mfma_f32_16x16x32_bf16((a), (b), (c), 0, 0, 0)

__launch_bounds__(512, 1)
__global__ void augru_kernel(const float* __restrict__ X,    // [B,T,D]
                             const float* __restrict__ ATT,  // [B,T,1]
                             const float* __restrict__ GK,   // [256,256]
                             const float* __restrict__ GB,   // [256]
                             const float* __restrict__ CK,   // [256,128]
                             const float* __restrict__ CB,   // [128]
                             const int*   __restrict__ SL,   // [B,1]
                             float* __restrict__ OUT) {      // [B,T,D]
    __shared__ short hb [16 * BS];      // h  (bf16 mirror, A-frag source)
    __shared__ short rhb[16 * BS];      // r*h (bf16, A-frag source)
    __shared__ short xb [2][16 * BS];   // x tile; slot s&1 holds x(s)
    __shared__ float abuf[2][16];       // holds (1 - a)
    __shared__ int   lenbuf[16];

    const int tid  = threadIdx.x;
    const int wid  = tid >> 6;          // 0..7
    const int lane = tid & 63;
    const int lm   = lane & 15;
    const int q    = lane >> 4;
    const int b0   = blockIdx.x * 16;
    const int ccol = 16 * wid + lm;     // wave's owned column

    // ---------- preload weight B-frags (B[k][n]: n=lane&15, k=q*8+j) ----------
    short8 fgx0[4], fgx1[4], fgh0[4], fgh1[4], fcx[4], fch[4];
#pragma unroll
    for (int ks = 0; ks < 4; ++ks) {
        short8 v0, v1, v2, v3, v4, v5;
#pragma unroll
        for (int j = 0; j < 8; ++j) {
            const int k = ks * 32 + q * 8 + j;
            v0[j] = f2bf(GK[k * 256 + ccol]);               // x-part, r col
            v1[j] = f2bf(GK[k * 256 + 128 + ccol]);         // x-part, u col
            v2[j] = f2bf(GK[(128 + k) * 256 + ccol]);       // h-part, r col
            v3[j] = f2bf(GK[(128 + k) * 256 + 128 + ccol]); // h-part, u col
            v4[j] = f2bf(CK[k * 128 + ccol]);               // cand x-part
            v5[j] = f2bf(CK[(128 + k) * 128 + ccol]);       // cand rh-part
        }
        fgx0[ks] = v0; fgx1[ks] = v1; fgh0[ks] = v2; fgh1[ks] = v3;
        fcx[ks] = v4;  fch[ks] = v5;
    }
    const float pb0 = GB[ccol]       * NL2E;
    const float pb1 = GB[128 + ccol] * NL2E;
    const float cbp = CB[ccol]       * N2L2E;

    // ---------- init LDS ----------
    for (int i = tid; i < 16 * BS; i += 512) hb[i] = 0;
    if (tid < 16) {
        lenbuf[tid]  = SL[b0 + tid];
        abuf[0][tid] = 1.0f - ATT[(size_t)(b0 + tid) * Tn];
    }
    const int prow = tid >> 5;            // x staging: row 0..15
    const int pcol = (tid & 31) * 4;      // 4 consecutive floats
    {   // stage x(0) into xb[0]
        float4 v = *(const float4*)(X + ((size_t)(b0 + prow) * Tn + 0) * Dn + pcol);
        uint2 pp; pp.x = cvt_pk_bf16(v.x, v.y); pp.y = cvt_pk_bf16(v.z, v.w);
        *(uint2*)&xb[0][prow * BS + pcol] = pp;
    }
    __syncthreads();

    int len_i[4];
    float h_reg[4] = {0.f, 0.f, 0.f, 0.f};   // master h: rows q*4+i, col ccol
    unsigned out_off[4];                     // running OUT offsets
#pragma unroll
    for (int i = 0; i < 4; ++i) {
        len_i[i]   = lenbuf[q * 4 + i];
        out_off[i] = (unsigned)(((b0 + q * 4 + i) * Tn) * Dn + ccol);
    }

    // ---------- prologue: x-partials for t=0; stage x(1) ----------
    f32x4 gxA0 = {0,0,0,0}, gxA1 = {0,0,0,0}, cxA = {0,0,0,0};
    f32x4 gxB0, gxB1, cxB;
    {
        short8 ax0[4];
#pragma unroll
        for (int ks = 0; ks < 4; ++ks)
            ax0[ks] = *(const short8*)&xb[0][lm * BS + ks * 32 + q * 8];
#pragma unroll
        for (int ks = 0; ks < 4; ++ks) {
            gxA0 = MFMA_(ax0[ks], fgx0[ks], gxA0);
            gxA1 = MFMA_(ax0[ks], fgx1[ks], gxA1);
            cxA  = MFMA_(ax0[ks], fcx[ks],  cxA);
        }
        float4 v = *(const float4*)(X + ((size_t)(b0 + prow) * Tn + 1) * Dn + pcol);
        uint2 pp; pp.x = cvt_pk_bf16(v.x, v.y); pp.y = cvt_pk_bf16(v.z, v.w);
        *(uint2*)&xb[1][prow * BS + pcol] = pp;
    }
    __syncthreads();

#define STEP_BODY(t, GIN0, GIN1, CIN, GOUT0, GOUT1, COUT)                         \
    {                                                                             \
        const int cur = (t) & 1, nxt = cur ^ 1;                                   \
        const int tp1 = ((t) + 1 < Tn) ? (t) + 1 : Tn - 1;                        \
        const int tp2 = ((t) + 2 < Tn) ? (t) + 2 : Tn - 1;                        \
        float4 xpre = *(const float4*)(X + ((size_t)(b0 + prow) * Tn + tp2) * Dn + pcol); \
        float  apre = (tid < 16) ? ATT[(size_t)(b0 + tid) * Tn + tp1] : 0.0f;     \
        /* ---- P1 region: ONLY the h-part gate MFMAs (4-deep) + act ---- */      \
        short8 ah[4];                                                             \
        _Pragma("unroll")                                                         \
        for (int ks = 0; ks < 4; ++ks)                                            \
            ah[ks] = *(const short8*)&hb[lm * BS + ks * 32 + q * 8];              \
        f32x4 g0 = GIN0, g1 = GIN1;                                               \
        _Pragma("unroll")                                                         \
        for (int ks = 0; ks < 4; ++ks) {                                          \
            g0 = MFMA_(ah[ks], fgh0[ks], g0);                                     \
            g1 = MFMA_(ah[ks], fgh1[ks], g1);                                     \
        }                                                                         \
        /* activations: wave-uniform; r,u for col ccol in the owning lane */      \
        float am[4], up[4], rhv[4];                                               \
        _Pragma("unroll")                                                         \
        for (int i = 0; i < 4; ++i) am[i] = abuf[cur][q * 4 + i];   /* = 1-a */   \
        _Pragma("unroll")                                                         \
        for (int i = 0; i < 4; ++i) {                                             \
            const float e0 = __builtin_amdgcn_exp2f(fmaf(g0[i], NL2E, pb0));      \
            rhv[i] = __builtin_amdgcn_rcpf(1.0f + e0) * h_reg[i];                 \
            const float e1 = __builtin_amdgcn_exp2f(fmaf(g1[i], NL2E, pb1));      \
            up[i] = am[i] * __builtin_amdgcn_rcpf(1.0f + e1);                     \
        }                                                                         \
        {                                                                         \
            const unsigned pA_ = cvt_pk_bf16(rhv[0], rhv[1]);                     \
            const unsigned pB_ = cvt_pk_bf16(rhv[2], rhv[3]);                     \
            rhb[(q * 4 + 0) * BS + ccol] = (short)pA_;                            \
            rhb[(q * 4 + 1) * BS + ccol] = (short)(pA_ >> 16);                    \
            rhb[(q * 4 + 2) * BS + ccol] = (short)pB_;                            \
            rhb[(q * 4 + 3) * BS + ccol] = (short)(pB_ >> 16);                    \
        }                                                                         \
        barrier_lds();                                                            \
        /* ---- P2 region: cand chain + x-partial MFMAs under update VALU ---- */ \
        short8 arh[4], axn[4];                                                    \
        _Pragma("unroll")                                                         \
        for (int ks = 0; ks < 4; ++ks) {                                          \
            arh[ks] = *(const short8*)&rhb[lm * BS + ks * 32 + q * 8];            \
            axn[ks] = *(const short8*)&xb[nxt][lm * BS + ks * 32 + q * 8];        \
        }                                                                         \
        f32x4 cc = CIN;                                                           \
        _Pragma("unroll")                                                         \
        for (int ks = 0; ks < 4; ++ks)                                            \
            cc = MFMA_(arh[ks], fch[ks], cc);                                     \
        f32x4 n0 = {0,0,0,0}, n1 = {0,0,0,0}, n2 = {0,0,0,0};                     \
        _Pragma("unroll")                                                         \
        for (int ks = 0; ks < 4; ++ks) {                                          \
            n0 = MFMA_(axn[ks], fgx0[ks], n0);                                    \
            n1 = MFMA_(axn[ks], fgx1[ks], n1);                                    \
            n2 = MFMA_(axn[ks], fcx[ks],  n2);                                    \
        }                                                                         \
        /* h update + output (register state; running OUT offsets) */             \
        float hxv[4];                                                             \
        _Pragma("unroll")                                                         \
        for (int i = 0; i < 4; ++i) {                                             \
            const float e  = __builtin_amdgcn_exp2f(fmaf(cc[i], N2L2E, cbp));     \
            const float cv = fmaf(2.0f, __builtin_amdgcn_rcpf(1.0f + e), -1.0f);  \
            const float hn = fmaf(up[i], h_reg[i] - cv, cv);                      \
            const bool valid = ((t) < len_i[i]);                                  \
            const float hnext = valid ? hn : h_reg[i];                            \
            OUT[out_off[i]] = valid ? hn : 0.0f;                                  \
            out_off[i] += Dn;                                                     \
            h_reg[i] = hnext;                                                     \
            hxv[i] = hnext;                                                       \
        }                                                                         \
        {                                                                         \
            const unsigned pA_ = cvt_pk_bf16(hxv[0], hxv[1]);                     \
            const unsigned pB_ = cvt_pk_bf16(hxv[2], hxv[3]);                     \
            hb[(q * 4 + 0) * BS + ccol] = (short)pA_;                             \
            hb[(q * 4 + 1) * BS + ccol] = (short)(pA_ >> 16);                     \
            hb[(q * 4 + 2) * BS + ccol] = (short)pB_;                             \
            hb[(q * 4 + 3) * BS + ccol] = (short)(pB_ >> 16);                     \
        }                                                                         \
        /* stage x(t+2) into xb[cur]; (1-a)(t+1) into abuf[nxt]            */     \
        /* write order matters for barrier_lds_c1: [hb x4, xb, abuf]       */     \
        {                                                                         \
            uint2 pp_;                                                            \
            pp_.x = cvt_pk_bf16(xpre.x, xpre.y);                                  \
            pp_.y = cvt_pk_bf16(xpre.z, xpre.w);                                  \
            *(uint2*)&xb[cur][prow * BS + pcol] = pp_;                            \
            if (tid < 16) abuf[nxt][tid] = 1.0f - apre;                           \
        }                                                                         \
        barrier_lds_c1();                                                         \
        GOUT0 = n0; GOUT1 = n1; COUT = n2;                                        \
    }

    // ---------- time loop (unrolled x2: static A/B partial-sum sets) ----------
    for (int t = 0; t < Tn; t += 2) {
        STEP_BODY(t,     gxA0, gxA1, cxA, gxB0, gxB1, cxB)
        STEP_BODY(t + 1, gxB0, gxB1, cxB, gxA0, gxA1, cxA)
    }
#undef STEP_BODY
}

extern "C" void kernel_launch(void* const* d_in, const int* in_sizes, int n_in,
                              void* d_out, int out_size, void* d_ws, size_t ws_size,
                              hipStream_t stream) {
    (void)in_sizes; (void)n_in; (void)d_ws; (void)ws_size; (void)out_size;
    const float* X   = (const float*)d_in[0];
    const float* ATT = (const float*)d_in[1];
    const float* GK  = (const float*)d_in[2];
    const float* GB  = (const float*)d_in[3];
    const float* CK  = (const float*)d_in[4];
    const float* CB  = (const float*)d_in[5];
    const int*   SL  = (const int*)d_in[6];
    float* OUT = (float*)d_out;

    augru_kernel<<<dim3(Bn / 16), dim3(512), 0, stream>>>(X, ATT, GK, GB, CK, CB, SL, OUT);
}